// Round 10
// baseline (340.013 us; speedup 1.0000x reference)
//
#include <hip/hip_runtime.h>
#include <hip/hip_bf16.h>

typedef unsigned short u16;
typedef __attribute__((ext_vector_type(8))) __bf16 bf16x8;
typedef __attribute__((ext_vector_type(16))) float f32x16;
typedef __attribute__((ext_vector_type(8))) unsigned short ushort8;

#define GM 8192
#define GN 4096
#define GK 4096
#define NT (GK / 64)  // 64 K-tiles of BK=64

__device__ __forceinline__ u16 f2bf(float f) {
  unsigned u = __float_as_uint(f);
  u += 0x7fffu + ((u >> 16) & 1u);
  return (u16)(u >> 16);
}

// ---- kernel 1: W_eff = bf16(W + 2 * (B @ A))   [4096][4096]
__global__ void build_weff(const float* __restrict__ W,
                           const float* __restrict__ lA,
                           const float* __restrict__ lB,
                           u16* __restrict__ Weff) {
  const int o = blockIdx.x;
  float b[8];
#pragma unroll
  for (int r = 0; r < 8; ++r) b[r] = 2.0f * lB[o * 8 + r];
  const float* wrow = W + (size_t)o * GK;
  u16* orow = Weff + (size_t)o * GK;
  for (int d = threadIdx.x * 4; d < GK; d += blockDim.x * 4) {
    float4 w = *reinterpret_cast<const float4*>(wrow + d);
    float a0 = w.x, a1 = w.y, a2 = w.z, a3 = w.w;
#pragma unroll
    for (int r = 0; r < 8; ++r) {
      float4 a = *reinterpret_cast<const float4*>(lA + r * GK + d);
      a0 += b[r] * a.x; a1 += b[r] * a.y; a2 += b[r] * a.z; a3 += b[r] * a.w;
    }
    ushort4 p;
    p.x = f2bf(a0); p.y = f2bf(a1); p.z = f2bf(a2); p.w = f2bf(a3);
    *reinterpret_cast<ushort4*>(orow + d) = p;
  }
}

// ---- kernel 2: x f32 -> bf16
__global__ void cvt_bf16(const float* __restrict__ x, u16* __restrict__ xb) {
  const size_t i = ((size_t)blockIdx.x * blockDim.x + threadIdx.x) * 8;
  float4 v0 = *reinterpret_cast<const float4*>(x + i);
  float4 v1 = *reinterpret_cast<const float4*>(x + i + 4);
  ushort8 o;
  o[0] = f2bf(v0.x); o[1] = f2bf(v0.y); o[2] = f2bf(v0.z); o[3] = f2bf(v0.w);
  o[4] = f2bf(v1.x); o[5] = f2bf(v1.y); o[6] = f2bf(v1.z); o[7] = f2bf(v1.w);
  *reinterpret_cast<ushort8*>(xb + i) = o;
}

// ---- kernel 3: 256x256-tile GEMM via 32x32x16 MFMA.
// R10: shape change, R7 schedule kept verbatim (one barrier + vmcnt(0)/tile,
// 1-deep staging, all 24 ds_read_b128 first, MFMA stream after).
// Rationale: 4 schedule variants all ~4330 cyc/tile with MFMA-busy ~2360 ~=
// the 16x16 shape floor (512x4.85). 32x32x16 floor = 256x8.07 = 2066 cyc
// and its measured ceiling is 2382-2495 TF vs 2075 — attack the floor.
// Frags: A row=l&31,k0=8*(l>>5); B col=l&31,k0=8*(l>>5) (analog of verified
// 16x16 mapping). C/D: col=l&31, row=(j&3)+8*(j>>2)+4*(l>>5) (m74/m101).
// 3-bit LDS swizzle kept: b128 served in 16-lane quarters spanning 16
// consecutive rows -> 8 slots x 2-way = free. XCD swizzle kept.
__device__ __forceinline__ void gload16(const u16* g, u16* l) {
  __builtin_amdgcn_global_load_lds(
      (const __attribute__((address_space(1))) void*)g,
      (__attribute__((address_space(3))) void*)l, 16, 0, 0);
}

#define BAR()                                  \
  do {                                         \
    asm volatile("" ::: "memory");             \
    __builtin_amdgcn_s_barrier();              \
    asm volatile("" ::: "memory");             \
  } while (0)

__global__ __launch_bounds__(512, 2) void gemm256(const u16* __restrict__ Ab,
                                                  const u16* __restrict__ Bb,
                                                  float* __restrict__ C) {
  // [buf][0=A,1=B][row*64 + k], 2*2*16384*2B = 128 KiB
  __shared__ u16 lds[2][2][256 * 64];

  const int tid = threadIdx.x;
  const int wv = tid >> 6;
  const int l = tid & 63;

  // XCD-aware swizzle: 512 blocks, 512 % 8 == 0 -> simple bijective form
  const int nwg = gridDim.x;
  const int cpx = nwg >> 3;
  const int wg = ((int)blockIdx.x & 7) * cpx + ((int)blockIdx.x >> 3);
  const int tm = wg >> 4;   // GN/256 = 16 tiles in N
  const int tn = wg & 15;

  const int wr = wv >> 2;   // 0..1  (M split: 128 rows/wave)
  const int wc = wv & 3;    // 0..3  (N split: 64 cols/wave)

  // --- staging constants (identical to R3..R9) ---
  const int srow = (wv << 3) + (l >> 3);
  const int srl = ((wv & 1) << 3) | (l >> 3);          // row bits 0..3
  const int skel = ((l & 7) << 3) ^ ((srl & 0xE) << 2);
  const u16* aG = Ab + (size_t)(tm * 256) * GK;
  const u16* bG = Bb + (size_t)(tn * 256) * GK;

  // --- reader constants (32-row fragments) ---
  const int fr32 = l & 31;                       // frag row/col within 32
  // kelem = (ks<<4) ^ fksw ; fksw = 8*(l>>5) XOR swizzle(row bits 1-3)
  const int fksw = (((l >> 5) & 1) << 3) ^ ((l & 0xE) << 2);
  const int arow = wr * 128 + fr32;
  const int brow = wc * 64 + fr32;

  // stage half-tile: th = K-tile, r: 0=A0,1=A1,2=B0,3=B1  (2 x gload16/wave)
  auto STAGE = [&](int th, int r) {
    const int k0 = th << 6;
    const u16* src = (r < 2 ? aG : bG) +
                     (size_t)((r & 1) * 128 + srow) * GK + k0 + skel;
    u16* dst = &lds[th & 1][r >> 1][(r & 1) * 8192 + wv * 512];
#pragma unroll
    for (int j = 0; j < 2; ++j)
      gload16(src + (size_t)(j * 64) * GK, dst + j * 4096);
  };

  // prologue: stage tile 0 only (1-deep pipeline)
  STAGE(0, 0); STAGE(0, 1); STAGE(0, 2); STAGE(0, 3);

  f32x16 acc[4][2] = {};         // [mt][nt] 32x32 tiles -> 128 VGPR
  bf16x8 af[4][4], bf[4][2];     // [ks][mt], [ks][nt] -> 96 VGPR

  for (int t = 0; t < NT; ++t) {
    // tile-boundary sync: own staging of buf(t) complete (vmcnt), then
    // barrier = everyone done staging t AND done reading t-1.
    asm volatile("s_waitcnt vmcnt(0)" ::: "memory");
    BAR();

    const u16* A = &lds[t & 1][0][0];
    const u16* B = &lds[t & 1][1][0];

    // ---- ALL 24 ds_read_b128 first, ks-major (consumption order) ----
#pragma unroll
    for (int ks = 0; ks < 4; ++ks) {
#pragma unroll
      for (int nt = 0; nt < 2; ++nt)
        bf[ks][nt] = *reinterpret_cast<const bf16x8*>(
            B + (brow + nt * 32) * 64 + ((ks << 4) ^ fksw));
#pragma unroll
      for (int mt = 0; mt < 4; ++mt)
        af[ks][mt] = *reinterpret_cast<const bf16x8*>(
            A + (arow + mt * 32) * 64 + ((ks << 4) ^ fksw));
    }

    // staging for t+1 (VMEM pipe; LDS-writes land during MFMA stream)
    if (t + 1 < NT) {
      STAGE(t + 1, 0); STAGE(t + 1, 1); STAGE(t + 1, 2); STAGE(t + 1, 3);
    }

    // ---- 32 MFMA, ks outer (acc reuse distance = 8 MFMAs) ----
    __builtin_amdgcn_s_setprio(1);
#pragma unroll
    for (int ks = 0; ks < 4; ++ks)
#pragma unroll
      for (int mt = 0; mt < 4; ++mt)
#pragma unroll
        for (int nt = 0; nt < 2; ++nt)
          acc[mt][nt] = __builtin_amdgcn_mfma_f32_32x32x16_bf16(
              af[ks][mt], bf[ks][nt], acc[mt][nt], 0, 0, 0);
    __builtin_amdgcn_s_setprio(0);
  }

  // epilogue: C/D layout col = l&31, row = (j&3) + 8*(j>>2) + 4*(l>>5)
  const int orow = tm * 256 + wr * 128 + 4 * (l >> 5);
  const int ocol = tn * 256 + wc * 64 + (l & 31);
#pragma unroll
  for (int mt = 0; mt < 4; ++mt)
#pragma unroll
    for (int nt = 0; nt < 2; ++nt) {
      float* cp = C + (size_t)(orow + mt * 32) * GN + (ocol + nt * 32);
#pragma unroll
      for (int j = 0; j < 16; ++j) {
        const int rr = (j & 3) + 8 * (j >> 2);
        cp[(size_t)rr * GN] = acc[mt][nt][j];
      }
    }
}

extern "C" void kernel_launch(void* const* d_in, const int* in_sizes, int n_in,
                              void* d_out, int out_size, void* d_ws, size_t ws_size,
                              hipStream_t stream) {
  const float* x  = (const float*)d_in[0];
  const float* W  = (const float*)d_in[1];
  const float* lA = (const float*)d_in[2];
  const float* lB = (const float*)d_in[3];
  float* out = (float*)d_out;

  u16* weff = (u16*)d_ws;
  u16* xb = (u16*)((char*)d_ws + (size_t)GN * GK * sizeof(u16));

  build_weff<<<GN, 256, 0, stream>>>(W, lA, lB, weff);
  cvt_bf16<<<(size_t)GM * GK / (256 * 8), 256, 0, stream>>>(x, xb);
  gemm256<<<(GM / 256) * (GN / 256), 512, 0, stream>>>(xb, weff, out);
}

// Round 11
// 291.548 us; speedup vs baseline: 1.1662x; 1.1662x over previous
//
#include <hip/hip_runtime.h>
#include <hip/hip_bf16.h>

typedef unsigned short u16;
typedef __attribute__((ext_vector_type(8))) __bf16 bf16x8;
typedef __attribute__((ext_vector_type(4))) float f32x4;
typedef __attribute__((ext_vector_type(8))) unsigned short ushort8;

#define GM 8192
#define GN 4096
#define GK 4096
#define NT (GK / 64)  // 64 K-tiles of BK=64

__device__ __forceinline__ u16 f2bf(float f) {
  unsigned u = __float_as_uint(f);
  u += 0x7fffu + ((u >> 16) & 1u);
  return (u16)(u >> 16);
}

// ---- kernel 1: W_eff = bf16(W + 2 * (B @ A))   [4096][4096]
__global__ void build_weff(const float* __restrict__ W,
                           const float* __restrict__ lA,
                           const float* __restrict__ lB,
                           u16* __restrict__ Weff) {
  const int o = blockIdx.x;
  float b[8];
#pragma unroll
  for (int r = 0; r < 8; ++r) b[r] = 2.0f * lB[o * 8 + r];
  const float* wrow = W + (size_t)o * GK;
  u16* orow = Weff + (size_t)o * GK;
  for (int d = threadIdx.x * 4; d < GK; d += blockDim.x * 4) {
    float4 w = *reinterpret_cast<const float4*>(wrow + d);
    float a0 = w.x, a1 = w.y, a2 = w.z, a3 = w.w;
#pragma unroll
    for (int r = 0; r < 8; ++r) {
      float4 a = *reinterpret_cast<const float4*>(lA + r * GK + d);
      a0 += b[r] * a.x; a1 += b[r] * a.y; a2 += b[r] * a.z; a3 += b[r] * a.w;
    }
    ushort4 p;
    p.x = f2bf(a0); p.y = f2bf(a1); p.z = f2bf(a2); p.w = f2bf(a3);
    *reinterpret_cast<ushort4*>(orow + d) = p;
  }
}

// ---- kernel 2: x f32 -> bf16
__global__ void cvt_bf16(const float* __restrict__ x, u16* __restrict__ xb) {
  const size_t i = ((size_t)blockIdx.x * blockDim.x + threadIdx.x) * 8;
  float4 v0 = *reinterpret_cast<const float4*>(x + i);
  float4 v1 = *reinterpret_cast<const float4*>(x + i + 4);
  ushort8 o;
  o[0] = f2bf(v0.x); o[1] = f2bf(v0.y); o[2] = f2bf(v0.z); o[3] = f2bf(v0.w);
  o[4] = f2bf(v1.x); o[5] = f2bf(v1.y); o[6] = f2bf(v1.z); o[7] = f2bf(v1.w);
  *reinterpret_cast<ushort8*>(xb + i) = o;
}

// ---- kernel 3: 256x256-tile GEMM, C[m][n] = sum_k A[m][k]*B[n][k]
// R11: R7 free-flow body (16x16x32, best-known 233us) + T19
// sched_group_barrier emission script. Diagnosis: MfmaUtil tracks
// MFMA-floor/total in every variant -> overlap-limited, not pipe-limited;
// source order emits read-clump then MFMA-clump. SGB pins per-wave
// interleave: DS6|MFMA4|DS6|MFMA12|VMEM16|DS4|MFMA16|DS8|MFMA32 --
// read groups land one group ahead of their consuming MFMAs.
// Stage is unconditional (clamped tile) so region counts match script.
// One barrier + vmcnt(0) per tile; 3-bit swizzle (0 conflicts); XCD swz.
__device__ __forceinline__ void gload16(const u16* g, u16* l) {
  __builtin_amdgcn_global_load_lds(
      (const __attribute__((address_space(1))) void*)g,
      (__attribute__((address_space(3))) void*)l, 16, 0, 0);
}

#define BAR()                                  \
  do {                                         \
    asm volatile("" ::: "memory");             \
    __builtin_amdgcn_s_barrier();              \
    asm volatile("" ::: "memory");             \
  } while (0)

#define SGB __builtin_amdgcn_sched_group_barrier

__global__ __launch_bounds__(512, 2) void gemm256(const u16* __restrict__ Ab,
                                                  const u16* __restrict__ Bb,
                                                  float* __restrict__ C) {
  // [buf][0=A,1=B][row*64 + k], 2*2*16384*2B = 128 KiB
  __shared__ u16 lds[2][2][256 * 64];

  const int tid = threadIdx.x;
  const int wv = tid >> 6;
  const int l = tid & 63;

  // XCD-aware swizzle: 512 blocks, 512 % 8 == 0 -> simple bijective form
  const int nwg = gridDim.x;
  const int cpx = nwg >> 3;
  const int wg = ((int)blockIdx.x & 7) * cpx + ((int)blockIdx.x >> 3);
  const int tm = wg >> 4;   // GN/256 = 16 tiles in N
  const int tn = wg & 15;

  const int wr = wv >> 2;   // 0..1  (M split)
  const int wc = wv & 3;    // 0..3  (N split)

  // --- staging constants ---
  const int srow = (wv << 3) + (l >> 3);
  const int srl = ((wv & 1) << 3) | (l >> 3);          // row bits 0..3
  const int skel = ((l & 7) << 3) ^ ((srl & 0xE) << 2);
  const u16* aG = Ab + (size_t)(tm * 256) * GK;
  const u16* bG = Bb + (size_t)(tn * 256) * GK;

  // --- reader constants ---
  const int frow = l & 15;
  const int fksw = ((l >> 4) << 3) ^ ((frow & 0xE) << 2);
  const int arow = wr * 128 + frow;
  const int brow = wc * 64 + frow;

  // stage half-tile: th = K-tile (clamped), r: 0=A0,1=A1,2=B0,3=B1
  auto STAGE = [&](int th, int r) {
    const int tc = th < NT ? th : NT - 1;  // clamp (tail garbage never read)
    const int k0 = tc << 6;
    const u16* src = (r < 2 ? aG : bG) +
                     (size_t)((r & 1) * 128 + srow) * GK + k0 + skel;
    u16* dst = &lds[th & 1][r >> 1][(r & 1) * 8192 + wv * 512];
#pragma unroll
    for (int j = 0; j < 2; ++j)
      gload16(src + (size_t)(j * 64) * GK, dst + j * 4096);
  };

  // prologue: stage tile 0 only (1-deep pipeline)
  STAGE(0, 0); STAGE(0, 1); STAGE(0, 2); STAGE(0, 3);

  f32x4 acc[8][4] = {};
  bf16x8 af_lo[4][2], af_hi[4][2], bfr0[2][2], bfr1[2][2];

  for (int t = 0; t < NT; ++t) {
    // tile-boundary sync: own staging of buf(t) complete (vmcnt), then
    // barrier = everyone done staging t AND done reading t-1.
    asm volatile("s_waitcnt vmcnt(0)" ::: "memory");
    BAR();

    const u16* A = &lds[t & 1][0][0];
    const u16* B = &lds[t & 1][1][0];

    // ---- ALL 24 ds_read_b128, consumption order ----
#pragma unroll
    for (int n = 0; n < 2; ++n)
#pragma unroll
      for (int s = 0; s < 2; ++s)
        bfr0[n][s] = *reinterpret_cast<const bf16x8*>(
            B + (brow + n * 16) * 64 + (fksw ^ (s << 5)));
#pragma unroll
    for (int m = 0; m < 4; ++m)
#pragma unroll
      for (int s = 0; s < 2; ++s)
        af_lo[m][s] = *reinterpret_cast<const bf16x8*>(
            A + (arow + m * 16) * 64 + (fksw ^ (s << 5)));
#pragma unroll
    for (int n = 0; n < 2; ++n)
#pragma unroll
      for (int s = 0; s < 2; ++s)
        bfr1[n][s] = *reinterpret_cast<const bf16x8*>(
            B + (brow + (n + 2) * 16) * 64 + (fksw ^ (s << 5)));
#pragma unroll
    for (int m = 0; m < 4; ++m)
#pragma unroll
      for (int s = 0; s < 2; ++s)
        af_hi[m][s] = *reinterpret_cast<const bf16x8*>(
            A + (arow + (m + 4) * 16) * 64 + (fksw ^ (s << 5)));

    // staging for t+1 (unconditional, clamped — uniform region counts)
    STAGE(t + 1, 0); STAGE(t + 1, 1); STAGE(t + 1, 2); STAGE(t + 1, 3);

    // ---- 64 MFMA in quadrant order ----
    __builtin_amdgcn_s_setprio(1);
#pragma unroll
    for (int m = 0; m < 4; ++m)
#pragma unroll
      for (int n = 0; n < 2; ++n)
#pragma unroll
        for (int s = 0; s < 2; ++s)
          acc[m][n] = __builtin_amdgcn_mfma_f32_16x16x32_bf16(
              af_lo[m][s], bfr0[n][s], acc[m][n], 0, 0, 0);
#pragma unroll
    for (int m = 0; m < 4; ++m)
#pragma unroll
      for (int n = 0; n < 2; ++n)
#pragma unroll
        for (int s = 0; s < 2; ++s)
          acc[m][n + 2] = __builtin_amdgcn_mfma_f32_16x16x32_bf16(
              af_lo[m][s], bfr1[n][s], acc[m][n + 2], 0, 0, 0);
#pragma unroll
    for (int m = 0; m < 4; ++m)
#pragma unroll
      for (int n = 0; n < 2; ++n)
#pragma unroll
        for (int s = 0; s < 2; ++s)
          acc[m + 4][n + 2] = __builtin_amdgcn_mfma_f32_16x16x32_bf16(
              af_hi[m][s], bfr1[n][s], acc[m + 4][n + 2], 0, 0, 0);
#pragma unroll
    for (int m = 0; m < 4; ++m)
#pragma unroll
      for (int n = 0; n < 2; ++n)
#pragma unroll
        for (int s = 0; s < 2; ++s)
          acc[m + 4][n] = __builtin_amdgcn_mfma_f32_16x16x32_bf16(
              af_hi[m][s], bfr0[n][s], acc[m + 4][n], 0, 0, 0);
    __builtin_amdgcn_s_setprio(0);

    // ---- T19 emission script for this region ----
    // masks: MFMA=0x8, VMEM_READ=0x20, DS_READ=0x100
    SGB(0x100, 6, 0);   // bfr0(4) + af_lo[0](2)
    SGB(0x008, 4, 0);   // Q0 m0 (operands: the 6 above)
    SGB(0x100, 6, 0);   // af_lo[1..3]
    SGB(0x008, 12, 0);  // Q0 m1-3
    SGB(0x020, 16, 0);  // 16 global_load_lds (issue early, land by t+1)
    SGB(0x100, 4, 0);   // bfr1
    SGB(0x008, 16, 0);  // Q1
    SGB(0x100, 8, 0);   // af_hi
    SGB(0x008, 16, 0);  // Q2
    SGB(0x008, 16, 0);  // Q3
  }

  // epilogue: C/D layout col = l&15, row = 4*(l>>4)+j
  const int orow = tm * 256 + wr * 128 + ((l >> 4) << 2);
  const int ocol = tn * 256 + wc * 64 + (l & 15);
#pragma unroll
  for (int m = 0; m < 8; ++m)
#pragma unroll
    for (int n = 0; n < 4; ++n) {
      float* cp = C + (size_t)(orow + m * 16) * GN + (ocol + n * 16);
#pragma unroll
      for (int j = 0; j < 4; ++j) cp[(size_t)j * GN] = acc[m][n][j];
    }
}

extern "C" void kernel_launch(void* const* d_in, const int* in_sizes, int n_in,
                              void* d_out, int out_size, void* d_ws, size_t ws_size,
                              hipStream_t stream) {
  const float* x  = (const float*)d_in[0];
  const float* W  = (const float*)d_in[1];
  const float* lA = (const float*)d_in[2];
  const float* lB = (const float*)d_in[3];
  float* out = (float*)d_out;

  u16* weff = (u16*)d_ws;
  u16* xb = (u16*)((char*)d_ws + (size_t)GN * GK * sizeof(u16));

  build_weff<<<GN, 256, 0, stream>>>(W, lA, lB, weff);
  cvt_bf16<<<(size_t)GM * GK / (256 * 8), 256, 0, stream>>>(x, xb);
  gemm256<<<(GM / 256) * (GN / 256), 512, 0, stream>>>(xb, weff, out);
}